// Round 3
// baseline (10924.040 us; speedup 1.0000x reference)
//
#include <hip/hip_runtime.h>
#include <stdint.h>

typedef unsigned short u16;
typedef uint32_t u32;
typedef __attribute__((ext_vector_type(8))) short short8;
typedef __attribute__((ext_vector_type(4))) float f32x4;

__device__ __forceinline__ float bf2f(u16 v) {
  union { u32 u; float f; } c; c.u = ((u32)v) << 16; return c.f;
}
__device__ __forceinline__ u16 f2bf(float f) {
  union { float f; u32 u; } c; c.f = f;
  u32 r = c.u + 0x7fffu + ((c.u >> 16) & 1u);  // RNE
  return (u16)(r >> 16);
}
__device__ __forceinline__ void mode_store(void* p, size_t idx, float v, u32 fm) {
  if (fm) ((float*)p)[idx] = v;
  else    ((u16*)p)[idx]   = f2bf(v);
}

enum { EPI_WS_F32 = 0, EPI_EMB = 1, EPI_SCORES = 2, EPI_OUT = 3 };

// ---- dtype detection: low u16 of fp32 data is random mantissa bits -> wild bf16 ----
__global__ void detect_kernel(const u32* __restrict__ x, u32* __restrict__ flag) {
  __shared__ int cnt;
  if (threadIdx.x == 0) cnt = 0;
  __syncthreads();
  int wild = 0;
  #pragma unroll
  for (int c = 0; c < 4; ++c) {
    u32 u = x[threadIdx.x * 4 + c];
    float a = fabsf(bf2f((u16)(u & 0xffff)));
    if (!(a <= 1e6f) || (a != 0.f && a < 1e-20f)) wild++;  // !(a<=..) catches NaN
  }
  atomicAdd(&cnt, wild);
  __syncthreads();
  if (threadIdx.x == 0) flag[0] = (cnt > 100) ? 1u : 0u;  // 1 = fp32 inputs
}

// ---- canonicalize any input array to f32 ----
__global__ void convert_kernel(const void* __restrict__ in, float* __restrict__ out,
                               int n, const u32* __restrict__ flag) {
  int i = blockIdx.x * 256 + threadIdx.x;
  if (i >= n) return;
  u32 fm = flag[0];
  out[i] = fm ? ((const float*)in)[i] : bf2f(((const u16*)in)[i]);
}

// ---- W[R=K][C=N] raw -> WT[N][K] in 3 bf16 planes (hi/mid/lo) ----
__global__ void trans_decomp_kernel(const void* __restrict__ in,
                                    u16* __restrict__ hi, u16* __restrict__ mid,
                                    u16* __restrict__ lo, int R, int C,
                                    const u32* __restrict__ flag) {
  __shared__ float t[32][33];
  u32 fm = flag[0];
  int x  = threadIdx.x & 31;
  int yq = threadIdx.x >> 5;
  int bx = blockIdx.x, by = blockIdx.y;
  #pragma unroll
  for (int yy = yq; yy < 32; yy += 8) {
    size_t src = (size_t)(by * 32 + yy) * C + bx * 32 + x;
    t[yy][x] = fm ? ((const float*)in)[src] : bf2f(((const u16*)in)[src]);
  }
  __syncthreads();
  #pragma unroll
  for (int yy = yq; yy < 32; yy += 8) {
    float v = t[x][yy];
    u16 h = f2bf(v);
    float r1 = v - bf2f(h);
    u16 m = f2bf(r1);
    u16 l = f2bf(r1 - bf2f(m));
    size_t dst = (size_t)(bx * 32 + yy) * R + by * 32 + x;
    hi[dst] = h; mid[dst] = m; lo[dst] = l;
  }
}

// ---- centers f32 -> 3 bf16 planes (same [K][D] layout, already B^T form) ----
__global__ void decomp_kernel(const float* __restrict__ in, u16* __restrict__ hi,
                              u16* __restrict__ mid, u16* __restrict__ lo, int n) {
  int i = blockIdx.x * 256 + threadIdx.x;
  if (i >= n) return;
  float v = in[i];
  u16 h = f2bf(v);
  float r1 = v - bf2f(h);
  u16 m = f2bf(r1);
  hi[i] = h; mid[i] = m; lo[i] = f2bf(r1 - bf2f(m));
}

// ---- c2[k] = sum_d centers[k][d]^2, from f32 centers, D=256 K=1024 ----
__global__ void c2_kernel(const float* __restrict__ cf, float* __restrict__ c2) {
  int w    = blockIdx.x * 4 + (threadIdx.x >> 6);
  int lane = threadIdx.x & 63;
  float4 v = *(const float4*)&cf[(size_t)w * 256 + lane * 4];
  float s = v.x * v.x + v.y * v.y + v.z * v.z + v.w * v.w;
  #pragma unroll
  for (int off = 32; off; off >>= 1) s += __shfl_down(s, off);
  if (lane == 0) c2[w] = s;
}

// C = act(A@W + bias). A is f32 (split into up to NA bf16 planes on the fly);
// W pre-split into up to NW bf16 planes [N][K]. Pass (pa,pw) used iff pa+pw<=PCAP.
// bf16-mode (fm==0): W planes beyond hi are zero -> nW=1; ARAW A exact bf16 -> nA=1.
// 128x128 tile, BK=32, 4 waves, 4x4 MFMA 16x16x32 per wave (m92/m97 layout).
template<int NA, int NW, int PCAP, int RELU, int EPI, int ARAW>
__global__ __launch_bounds__(256)
void gemm_kernel(const float* __restrict__ A,
                 const u16* __restrict__ W0, const u16* __restrict__ W1,
                 const u16* __restrict__ W2,
                 const float* __restrict__ bias, const float* __restrict__ c2p,
                 float* __restrict__ outws, void* __restrict__ dout, size_t doff,
                 const u32* __restrict__ flag, int M, int N, int K)
{
  constexpr int BK = 32;
  __shared__ __align__(16) u16 lds[(NA + NW) * 128 * BK];
  const u32 fm = flag[0];
  const int nA = fm ? NA : (ARAW ? 1 : NA);
  const int nW = fm ? NW : 1;
  const u16* Wp[3] = {W0, W1, W2};
  const int tid  = threadIdx.x;
  const int lane = tid & 63;
  const int wid  = tid >> 6;
  const int m0 = blockIdx.y * 128;
  const int n0 = blockIdx.x * 128;
  const int wm = (wid & 1) * 64;
  const int wn = (wid >> 1) * 64;

  f32x4 acc[4][4];
  #pragma unroll
  for (int i = 0; i < 4; ++i)
    #pragma unroll
    for (int j = 0; j < 4; ++j)
      acc[i][j] = f32x4{0.f, 0.f, 0.f, 0.f};

  for (int k0 = 0; k0 < K; k0 += BK) {
    __syncthreads();
    // stage A: 128x32 f32 = 1024 float4 chunks, 4/thread; decompose into nA planes
    {
      const float* Af = A + (size_t)m0 * K + k0;
      #pragma unroll
      for (int c = 0; c < 4; ++c) {
        int ci  = tid + c * 256;
        int row = ci >> 3;
        int col = (ci & 7) * 4;
        float4 v = *(const float4*)&Af[(size_t)row * K + col];
        float vv[4] = {v.x, v.y, v.z, v.w};
        int base = row * BK + col;
        u16 h[4];
        #pragma unroll
        for (int q = 0; q < 4; ++q) h[q] = f2bf(vv[q]);
        uint2 t;
        t.x = (u32)h[0] | ((u32)h[1] << 16);
        t.y = (u32)h[2] | ((u32)h[3] << 16);
        *(uint2*)&lds[base] = t;
        if (nA > 1) {
          float r1[4]; u16 m[4];
          #pragma unroll
          for (int q = 0; q < 4; ++q) { r1[q] = vv[q] - bf2f(h[q]); m[q] = f2bf(r1[q]); }
          t.x = (u32)m[0] | ((u32)m[1] << 16);
          t.y = (u32)m[2] | ((u32)m[3] << 16);
          *(uint2*)&lds[4096 + base] = t;
          if (nA > 2) {
            u16 l[4];
            #pragma unroll
            for (int q = 0; q < 4; ++q) l[q] = f2bf(r1[q] - bf2f(m[q]));
            t.x = (u32)l[0] | ((u32)l[1] << 16);
            t.y = (u32)l[2] | ((u32)l[3] << 16);
            *(uint2*)&lds[8192 + base] = t;
          }
        }
      }
    }
    // stage W planes: each 128x32 bf16 = 512 int4 chunks, 2/thread
    for (int pw = 0; pw < nW; ++pw) {
      const u16* src = Wp[pw] + (size_t)n0 * K + k0;
      #pragma unroll
      for (int c = 0; c < 2; ++c) {
        int ci  = tid + c * 256;
        int row = ci >> 2;
        int col = (ci & 3) * 8;
        *(int4*)&lds[(NA + pw) * 4096 + row * BK + col] =
            *(const int4*)&src[(size_t)row * K + col];
      }
    }
    __syncthreads();

    short8 bfrag[NW][4];
    for (int pw = 0; pw < nW; ++pw)
      #pragma unroll
      for (int j = 0; j < 4; ++j) {
        int r = wn + j * 16 + (lane & 15);
        bfrag[pw][j] = *(const short8*)&lds[(NA + pw) * 4096 + r * BK + (lane >> 4) * 8];
      }
    for (int pa = 0; pa < nA; ++pa) {
      short8 afrag[4];
      #pragma unroll
      for (int i = 0; i < 4; ++i) {
        int r = wm + i * 16 + (lane & 15);
        afrag[i] = *(const short8*)&lds[pa * 4096 + r * BK + (lane >> 4) * 8];
      }
      for (int pw = 0; pw < nW; ++pw) {
        if (pa + pw > PCAP) continue;
        #pragma unroll
        for (int i = 0; i < 4; ++i)
          #pragma unroll
          for (int j = 0; j < 4; ++j)
            acc[i][j] = __builtin_amdgcn_mfma_f32_16x16x32_bf16(
                afrag[i], bfrag[pw][j], acc[i][j], 0, 0, 0);
      }
    }
  }

  // epilogue: C/D layout col=lane&15, row=(lane>>4)*4+reg
  #pragma unroll
  for (int i = 0; i < 4; ++i) {
    int rbase = m0 + wm + i * 16 + ((lane >> 4) * 4);
    #pragma unroll
    for (int j = 0; j < 4; ++j) {
      int col = n0 + wn + j * 16 + (lane & 15);
      float bv = 0.f, c2v = 0.f;
      if (EPI != EPI_SCORES) bv = bias[col];
      if (EPI == EPI_SCORES) c2v = c2p[col];
      #pragma unroll
      for (int r = 0; r < 4; ++r) {
        float v = acc[i][j][r] + bv;
        if (RELU) v = fmaxf(v, 0.f);
        size_t idx = (size_t)(rbase + r) * N + col;
        if (EPI == EPI_SCORES)      outws[idx] = c2v - 2.f * v;
        else if (EPI == EPI_WS_F32) outws[idx] = v;
        else if (EPI == EPI_EMB)  { outws[idx] = v; mode_store(dout, doff + idx, v, fm); }
        else                        mode_store(dout, doff + idx, v, fm);
      }
    }
  }
}

// per-row argmin over K=1024 (np first-index tie-break) -> one-hot at d_out element offset
__global__ void argmin_onehot(const float* __restrict__ scores, void* __restrict__ dout,
                              size_t doff, const u32* __restrict__ flag) {
  const int Kc = 1024;
  u32 fm  = flag[0];
  int row  = blockIdx.x * 4 + (threadIdx.x >> 6);
  int lane = threadIdx.x & 63;
  const float* s = scores + (size_t)row * Kc;
  float bestv = 3.4e38f;
  int   besti = Kc;
  #pragma unroll
  for (int base = 0; base < Kc; base += 256) {
    float4 v = *(const float4*)&s[base + lane * 4];
    int i0 = base + lane * 4;
    if (v.x < bestv) { bestv = v.x; besti = i0; }
    if (v.y < bestv) { bestv = v.y; besti = i0 + 1; }
    if (v.z < bestv) { bestv = v.z; besti = i0 + 2; }
    if (v.w < bestv) { bestv = v.w; besti = i0 + 3; }
  }
  #pragma unroll
  for (int off = 32; off; off >>= 1) {
    float ov = __shfl_down(bestv, off);
    int   oi = __shfl_down(besti, off);
    if (ov < bestv || (ov == bestv && oi < besti)) { bestv = ov; besti = oi; }
  }
  besti = __shfl(besti, 0);
  size_t eb = doff + (size_t)row * Kc + lane * 16;
  if (fm) {
    float* op = (float*)dout;
    #pragma unroll
    for (int q = 0; q < 16; ++q)
      op[eb + q] = (lane * 16 + q == besti) ? 1.0f : 0.0f;
  } else {
    u16* op = (u16*)dout + eb;
    uint32_t w[8];
    #pragma unroll
    for (int q = 0; q < 8; ++q) {
      int c0 = lane * 16 + q * 2;
      w[q] = ((c0 == besti) ? 0x3F80u : 0u) | (((c0 + 1 == besti) ? 0x3F80u : 0u) << 16);
    }
    *(uint4*)op       = make_uint4(w[0], w[1], w[2], w[3]);
    *(uint4*)(op + 8) = make_uint4(w[4], w[5], w[6], w[7]);
  }
}

extern "C" void kernel_launch(void* const* d_in, const int* in_sizes, int n_in,
                              void* d_out, int out_size, void* d_ws, size_t ws_size,
                              hipStream_t stream) {
  const int Bn = 8192;
  const int ENC[5] = {1024, 2048, 1024, 512, 256};
  const int DEC[5] = {256, 512, 1024, 2048, 1024};

  const void* x = d_in[0];
  const void *We[4], *be[4], *Wd[4], *bd[4];
  for (int i = 0; i < 4; ++i) { We[i] = d_in[1 + 2 * i]; be[i] = d_in[2 + 2 * i]; }
  for (int i = 0; i < 4; ++i) { Wd[i] = d_in[9 + 2 * i]; bd[i] = d_in[10 + 2 * i]; }
  const void* centers = d_in[17];

  // ---- fixed workspace carve ----
  char* wsb = (char*)d_ws;
  size_t o = 0;
  auto carve = [&](size_t bytes) { void* p = wsb + o; o += (bytes + 63) & ~size_t(63); return p; };
  u32* flag = (u32*)carve(64);
  u16 *WTe[4][3], *WTd[4][3];
  for (int i = 0; i < 4; ++i)
    for (int p = 0; p < 3; ++p) WTe[i][p] = (u16*)carve((size_t)ENC[i] * ENC[i + 1] * 2);
  for (int i = 0; i < 4; ++i)
    for (int p = 0; p < 3; ++p) WTd[i][p] = (u16*)carve((size_t)DEC[i] * DEC[i + 1] * 2);
  float* bef[4]; float* bdf[4];
  for (int i = 0; i < 4; ++i) bef[i] = (float*)carve((size_t)ENC[i + 1] * 4);
  for (int i = 0; i < 4; ++i) bdf[i] = (float*)carve((size_t)DEC[i + 1] * 4);
  float* cenf = (float*)carve(1024 * 256 * 4);
  u16* cen[3];
  for (int p = 0; p < 3; ++p) cen[p] = (u16*)carve(1024 * 256 * 2);
  float* c2 = (float*)carve(1024 * 4);

  // ---- chunk size from remaining ws (per-chunk: CH*19456 bytes) ----
  size_t rem = (ws_size > o) ? ws_size - o - 4096 : 0;
  int CH = 256;
  for (int c = 8192; c >= 256; c >>= 1)
    if ((size_t)c * 19456 <= rem) { CH = c; break; }
  const int nch = Bn / CH;
  float* xf  = (float*)carve((size_t)CH * 1024 * 4);
  float* h1  = (float*)carve((size_t)CH * 2048 * 4);
  float* h2  = (float*)carve((size_t)CH * 1024 * 4);
  float* h3  = (float*)carve((size_t)CH * 512 * 4);
  float* emb = (float*)carve((size_t)CH * 256 * 4);
  // overlays (stream-ordered reuse of dead regions):
  float* scores = h1;   // CH*1024 f32; h1 dead after e2
  float* g1 = h3;       // CH*512  f32; h3 dead after e4 (same size)
  float* g2 = h2;       // CH*1024 f32; h2 dead after e3 (same size)
  float* g3 = h1;       // CH*2048 f32; h1/scores dead after argmin (same size)

  const size_t off_emb    = (size_t)Bn * 1024;
  const size_t off_labels = (size_t)Bn * 1280;

  // ---- prep: detect dtype, convert/transpose/decompose params ----
  detect_kernel<<<1, 256, 0, stream>>>((const u32*)x, flag);
  for (int i = 0; i < 4; ++i)
    trans_decomp_kernel<<<dim3(ENC[i + 1] / 32, ENC[i] / 32), 256, 0, stream>>>(
        We[i], WTe[i][0], WTe[i][1], WTe[i][2], ENC[i], ENC[i + 1], flag);
  for (int i = 0; i < 4; ++i)
    trans_decomp_kernel<<<dim3(DEC[i + 1] / 32, DEC[i] / 32), 256, 0, stream>>>(
        Wd[i], WTd[i][0], WTd[i][1], WTd[i][2], DEC[i], DEC[i + 1], flag);
  for (int i = 0; i < 4; ++i) {
    convert_kernel<<<(ENC[i + 1] + 255) / 256, 256, 0, stream>>>(be[i], bef[i], ENC[i + 1], flag);
    convert_kernel<<<(DEC[i + 1] + 255) / 256, 256, 0, stream>>>(bd[i], bdf[i], DEC[i + 1], flag);
  }
  convert_kernel<<<(1024 * 256) / 256, 256, 0, stream>>>(centers, cenf, 1024 * 256, flag);
  decomp_kernel<<<(1024 * 256) / 256, 256, 0, stream>>>(cenf, cen[0], cen[1], cen[2], 1024 * 256);
  c2_kernel<<<256, 256, 0, stream>>>(cenf, c2);

  const int GY = CH / 128;
  for (int c = 0; c < nch; ++c) {
    const char* xc = (const char*)x;  // element offset applied inside convert via pointer math
    // x chunk -> f32 (element offset differs by dtype; pass adjusted pointer per mode is
    // impossible host-side, so convert with element-indexed kernel over a chunk view):
    // we pass base + element offset computed per-mode inside a dedicated kernel call:
    // simplest: convert from element offset using a wrapper pointer trick — use full-array
    // indexing: launch over CH*1024 elements starting at element c*CH*1024.
    {
      // convert_kernel indexes [0,n); shift base per mode is handled by passing both
      // possible pointers... instead: one kernel with element offset baked in:
      // reuse convert_kernel by passing base pointers advanced per-mode is not possible,
      // so launch a grid covering the chunk and add offset inside via blockIdx trick:
      // easiest correct path: full-x convert on chunk 0 only sized CH; for c>0 we need
      // offset — use a small dedicated kernel below.
    }
    // dedicated offset convert:
    struct {} _;
    extern __global__ void convert_off_kernel(const void*, float*, int, size_t, const u32*);
    convert_off_kernel<<<(CH * 1024) / 256, 256, 0, stream>>>(
        x, xf, CH * 1024, (size_t)c * CH * 1024, flag);

    gemm_kernel<3, 3, 2, 1, EPI_WS_F32, 1><<<dim3(16, GY), 256, 0, stream>>>(
        xf, WTe[0][0], WTe[0][1], WTe[0][2], bef[0], nullptr, h1, nullptr, 0, flag, CH, 2048, 1024);
    gemm_kernel<3, 3, 2, 1, EPI_WS_F32, 0><<<dim3(8, GY), 256, 0, stream>>>(
        h1, WTe[1][0], WTe[1][1], WTe[1][2], bef[1], nullptr, h2, nullptr, 0, flag, CH, 1024, 2048);
    gemm_kernel<3, 3, 2, 1, EPI_WS_F32, 0><<<dim3(4, GY), 256, 0, stream>>>(
        h2, WTe[2][0], WTe[2][1], WTe[2][2], bef[2], nullptr, h3, nullptr, 0, flag, CH, 512, 1024);
    gemm_kernel<3, 3, 2, 0, EPI_EMB, 0><<<dim3(2, GY), 256, 0, stream>>>(
        h3, WTe[3][0], WTe[3][1], WTe[3][2], bef[3], nullptr, emb, d_out,
        off_emb + (size_t)c * CH * 256, flag, CH, 256, 512);

    gemm_kernel<3, 3, 2, 0, EPI_SCORES, 0><<<dim3(8, GY), 256, 0, stream>>>(
        emb, cen[0], cen[1], cen[2], nullptr, c2, scores, nullptr, 0, flag, CH, 1024, 256);
    argmin_onehot<<<CH / 4, 256, 0, stream>>>(scores, d_out,
        off_labels + (size_t)c * CH * 1024, flag);

    gemm_kernel<2, 2, 1, 1, EPI_WS_F32, 0><<<dim3(4, GY), 256, 0, stream>>>(
        emb, WTd[0][0], WTd[0][1], nullptr, bdf[0], nullptr, g1, nullptr, 0, flag, CH, 512, 256);
    gemm_kernel<2, 2, 1, 1, EPI_WS_F32, 0><<<dim3(8, GY), 256, 0, stream>>>(
        g1, WTd[1][0], WTd[1][1], nullptr, bdf[1], nullptr, g2, nullptr, 0, flag, CH, 1024, 512);
    gemm_kernel<2, 2, 1, 1, EPI_WS_F32, 0><<<dim3(16, GY), 256, 0, stream>>>(
        g2, WTd[2][0], WTd[2][1], nullptr, bdf[2], nullptr, g3, nullptr, 0, flag, CH, 2048, 1024);
    gemm_kernel<2, 2, 1, 0, EPI_OUT, 0><<<dim3(8, GY), 256, 0, stream>>>(
        g3, WTd[3][0], WTd[3][1], nullptr, bdf[3], nullptr, nullptr, d_out,
        (size_t)c * CH * 1024, flag, CH, 1024, 2048);
  }

  (void)in_sizes; (void)n_in; (void)out_size;
}

// x chunk -> f32 with element offset (dtype-dependent base indexing done device-side)
__global__ void convert_off_kernel(const void* __restrict__ in, float* __restrict__ out,
                                   int n, size_t eoff, const u32* __restrict__ flag) {
  int i = blockIdx.x * 256 + threadIdx.x;
  if (i >= n) return;
  u32 fm = flag[0];
  out[i] = fm ? ((const float*)in)[eoff + i] : bf2f(((const u16*)in)[eoff + i]);
}